// Round 3
// baseline (1145.446 us; speedup 1.0000x reference)
//
#include <hip/hip_runtime.h>
#include <hip/hip_bf16.h>
#include <stdint.h>

// Sizes fixed by the problem
#define B_N 4096
#define P_N 32
#define C_N 512
#define LABC 0.1f       // 2/(ALPHA*NORM)
#define N_II 528        // 33*32/2 upper-triangle 128x128 tiles of the 4096x4096 Gram
// Interleave ii blocks 1-in-9 through the grid so the compute-bound ii tiles
// overlap the memory-bound pf stream.
#define GRID_TOTAL (N_II * 9)   // 4752
#define N_TTSLOT (GRID_TOTAL - N_II) // 4224 tt slots (4096 real + 128 zero-writers)

typedef float  floatx4 __attribute__((ext_vector_type(4)));
typedef __bf16 bf16x8  __attribute__((ext_vector_type(8)));

__device__ __forceinline__ unsigned short f2bf(float x) {
    return __builtin_bit_cast(unsigned short, __float2bfloat16(x));
}
__device__ __forceinline__ uint4 pack8(const float4& v0, const float4& v1) {
    uint4 pk;
    pk.x = (unsigned)f2bf(v0.x) | ((unsigned)f2bf(v0.y) << 16);
    pk.y = (unsigned)f2bf(v0.z) | ((unsigned)f2bf(v0.w) << 16);
    pk.z = (unsigned)f2bf(v1.x) | ((unsigned)f2bf(v1.y) << 16);
    pk.w = (unsigned)f2bf(v1.z) | ((unsigned)f2bf(v1.w) << 16);
    return pk;
}
__device__ __forceinline__ void bfly_reduce2(float& a, float& b) {
#pragma unroll
    for (int m = 1; m < 64; m <<= 1) {
        a += __shfl_xor(a, m, 64);
        b += __shfl_xor(b, m, 64);
    }
}
__device__ __forceinline__ void bfly_reduce1(float& a) {
#pragma unroll
    for (int m = 1; m < 64; m <<= 1) a += __shfl_xor(a, m, 64);
}

// ---------------- kernel A: normalize feats -> bf16, mae partials, zero ctr ----------------
__global__ __launch_bounds__(256) void k_prep(const float* __restrict__ feats,
                                              const float* __restrict__ pred,
                                              const float* __restrict__ targ,
                                              unsigned short* __restrict__ fb,
                                              float* __restrict__ maePart,
                                              unsigned* __restrict__ ctr) {
    const int wave = threadIdx.x >> 6, lane = threadIdx.x & 63;
    const int row = blockIdx.x * 4 + wave;
    const float* src = feats + (size_t)row * C_N + lane * 8;
    float4 v0 = *(const float4*)src;
    float4 v1 = *(const float4*)(src + 4);
    float ss = v0.x*v0.x + v0.y*v0.y + v0.z*v0.z + v0.w*v0.w
             + v1.x*v1.x + v1.y*v1.y + v1.z*v1.z + v1.w*v1.w;
    bfly_reduce1(ss);
    const float inv = rsqrtf(fmaxf(ss, 1e-24f));
    float4 n0 = {v0.x*inv, v0.y*inv, v0.z*inv, v0.w*inv};
    float4 n1 = {v1.x*inv, v1.y*inv, v1.z*inv, v1.w*inv};
    *(uint4*)(fb + (size_t)row * C_N + lane * 8) = pack8(n0, n1);

    if (wave == 0) {  // mae partials for this block's 4 rows
        float v = 0.f;
        if (lane < 4) {
            const int r = blockIdx.x * 4 + lane;
            v = fabsf(pred[r] - targ[r]);
        }
        v += __shfl_xor(v, 1, 64);
        v += __shfl_xor(v, 2, 64);
        if (lane == 0) maePart[blockIdx.x] = v;
    }
    if (blockIdx.x == 0 && threadIdx.x == 0) *ctr = 0u;  // workspace is poisoned each iter
}

// ---------------- kernel B: fused ii + tt/it (1-in-9) + last-block finalize ----------------
#define APAD 130
struct TTsm {
    unsigned short pfs[64 * 33 * 8];  // [chunk 0..63][row 0..32][8 bf16]; row 32 = f_norm
    float psS[P_N];
    float rdiag[P_N];
    float redT[4], redI[4];
};
struct IIsm {
    unsigned short As[4 * APAD * 8];
    unsigned short Bs[4 * APAD * 8];
    float tm[128], tn[128];
    float red[4];
};
union SMu { TTsm tt; IIsm ii; };

__global__ __launch_bounds__(256) void k_fused(const float* __restrict__ pf_g,
                                               const float* __restrict__ ps_g,
                                               const float* __restrict__ targets,
                                               const unsigned short* __restrict__ fb,
                                               double* __restrict__ partII,
                                               double* __restrict__ partTT,
                                               double* __restrict__ partIT,
                                               const float* __restrict__ maePart,
                                               unsigned* __restrict__ ctr,
                                               float* __restrict__ out) {
    __shared__ __align__(16) SMu sm;
    __shared__ unsigned isLast;
    __shared__ double finA[4], finB[4], finC[4];
    __shared__ float finM[4];
    const int tid = threadIdx.x, wave = tid >> 6, lane = tid & 63;
    const int quad = lane >> 4, l15 = lane & 15;
    const int bid = blockIdx.x;
    const bool isII = (bid % 9) == 0;

    if (isII) {
        // ================= image-image: 128x128 upper-triangle Gram tile =================
        IIsm& S = sm.ii;
        int bm = 0, rem = bid / 9;
        while (rem >= 32 - bm) { rem -= 32 - bm; ++bm; }
        const int bn = bm + rem;
        const int wr = wave >> 1, wc = wave & 1;
        const int mbase = bm * 128, nbase = bn * 128;

        if (tid < 128) S.tm[tid] = targets[mbase + tid];
        else           S.tn[tid - 128] = targets[nbase + tid - 128];

        const int row = tid >> 1, half = tid & 1;
        const unsigned short* aSrc = fb + (size_t)(mbase + row) * C_N + half * 16;
        const unsigned short* bSrc = fb + (size_t)(nbase + row) * C_N + half * 16;
        const int c0 = half * 2, c1 = half * 2 + 1;

        floatx4 accv[16];
#pragma unroll
        for (int i = 0; i < 16; ++i) accv[i] = (floatx4){0.f, 0.f, 0.f, 0.f};

        uint4 a0 = *(const uint4*)(aSrc);
        uint4 a1 = *(const uint4*)(aSrc + 8);
        uint4 b0 = *(const uint4*)(bSrc);
        uint4 b1 = *(const uint4*)(bSrc + 8);

        for (int ks = 0; ks < 16; ++ks) {
            __syncthreads();
            *(uint4*)&S.As[((size_t)c0 * APAD + row) * 8] = a0;
            *(uint4*)&S.As[((size_t)c1 * APAD + row) * 8] = a1;
            *(uint4*)&S.Bs[((size_t)c0 * APAD + row) * 8] = b0;
            *(uint4*)&S.Bs[((size_t)c1 * APAD + row) * 8] = b1;
            __syncthreads();
            if (ks < 15) {
                const int off = (ks + 1) * 32;
                a0 = *(const uint4*)(aSrc + off);
                a1 = *(const uint4*)(aSrc + off + 8);
                b0 = *(const uint4*)(bSrc + off);
                b1 = *(const uint4*)(bSrc + off + 8);
            }
            bf16x8 af[4], bfv[4];
#pragma unroll
            for (int t = 0; t < 4; ++t)
                af[t] = __builtin_bit_cast(bf16x8, *(const uint4*)&S.As[((size_t)quad * APAD + wr * 64 + t * 16 + l15) * 8]);
#pragma unroll
            for (int t = 0; t < 4; ++t)
                bfv[t] = __builtin_bit_cast(bf16x8, *(const uint4*)&S.Bs[((size_t)quad * APAD + wc * 64 + t * 16 + l15) * 8]);
#pragma unroll
            for (int ti = 0; ti < 4; ++ti)
#pragma unroll
                for (int tj = 0; tj < 4; ++tj)
                    accv[ti * 4 + tj] = __builtin_amdgcn_mfma_f32_16x16x32_bf16(af[ti], bfv[tj], accv[ti * 4 + tj], 0, 0, 0);
        }

        float s = 0.f;
#pragma unroll
        for (int ti = 0; ti < 4; ++ti)
#pragma unroll
            for (int tj = 0; tj < 4; ++tj)
#pragma unroll
                for (int r = 0; r < 4; ++r) {
                    const int p = wr * 64 + ti * 16 + quad * 4 + r;
                    const int q = wc * 64 + tj * 16 + l15;
                    const float lab = 1.f - LABC * fabsf(S.tm[p] - S.tn[q]);
                    s += fabsf(accv[ti * 4 + tj][r] - lab);
                }
        if (bm != bn) s *= 2.f;
        bfly_reduce1(s);
        if (lane == 0) S.red[wave] = s;
        __syncthreads();
        if (tid == 0) partII[bid / 9] = (double)(S.red[0] + S.red[1] + S.red[2] + S.red[3]);
    } else {
        // ================= text-text + image-text for one b =================
        const int b = bid - (bid / 9) - 1;   // dense 0..4223 over tt slots
        TTsm& S = sm.tt;
        if (b < B_N) {
            // Stage all global loads into registers first (16 x 16B in flight/thread).
            const float* base = pf_g + (size_t)b * P_N * C_N;
            uint4 st[16];
#pragma unroll
            for (int i = 0; i < 8; ++i) {
                const float* src = base + (wave * 8 + i) * C_N + lane * 8;
                st[2 * i]     = *(const uint4*)src;
                st[2 * i + 1] = *(const uint4*)(src + 4);
            }
            uint4 fReg = {0u, 0u, 0u, 0u};
            if (wave == 0) fReg = *(const uint4*)(fb + (size_t)b * C_N + lane * 8);
            if (tid < P_N) S.psS[tid] = ps_g[b * P_N + tid];
            const float tb = targets[b];

#pragma unroll
            for (int i = 0; i < 8; ++i) {
                const int r = wave * 8 + i;
                const float4 v0 = __builtin_bit_cast(float4, st[2 * i]);
                const float4 v1 = __builtin_bit_cast(float4, st[2 * i + 1]);
                *(uint4*)&S.pfs[((size_t)lane * 33 + r) * 8] = pack8(v0, v1);
            }
            if (wave == 0) *(uint4*)&S.pfs[((size_t)lane * 33 + 32) * 8] = fReg;
            __syncthreads();

            // Gram of raw-bf16 pf (4 tiles, one per wave) + f-row tiles on waves 0,1
            const int pt = (wave >> 1) * 16, qt = (wave & 1) * 16;
            const bool doF = (wave < 2);
            floatx4 acc4 = {0.f, 0.f, 0.f, 0.f};
            floatx4 accF = {0.f, 0.f, 0.f, 0.f};
            const uint4 zero4 = {0u, 0u, 0u, 0u};
#pragma unroll
            for (int kk = 0; kk < 16; ++kk) {
                const int ch = kk * 4 + quad;
                bf16x8 a = __builtin_bit_cast(bf16x8, *(const uint4*)&S.pfs[((size_t)ch * 33 + pt + l15) * 8]);
                bf16x8 bb = __builtin_bit_cast(bf16x8, *(const uint4*)&S.pfs[((size_t)ch * 33 + qt + l15) * 8]);
                acc4 = __builtin_amdgcn_mfma_f32_16x16x32_bf16(a, bb, acc4, 0, 0, 0);
                if (doF) {
                    uint4 fr = *(const uint4*)&S.pfs[((size_t)ch * 33 + 32) * 8];  // broadcast
                    bf16x8 af = __builtin_bit_cast(bf16x8, (l15 == 0) ? fr : zero4);
                    accF = __builtin_amdgcn_mfma_f32_16x16x32_bf16(af, bb, accF, 0, 0, 0);
                }
            }
            if (pt == qt) {
                if ((l15 >> 2) == quad) S.rdiag[pt + l15] = rsqrtf(fmaxf(acc4[l15 & 3], 1e-24f));
            }
            __syncthreads();

            float tt_sum = 0.f, it_sum = 0.f;
#pragma unroll
            for (int r = 0; r < 4; ++r) {
                const int p = pt + quad * 4 + r;
                const int q = qt + l15;
                const float val = acc4[r] * S.rdiag[p] * S.rdiag[q];
                const float lab = 1.f - LABC * fabsf(S.psS[p] - S.psS[q]);
                tt_sum += fabsf(val - lab);
            }
            if (doF && quad == 0) {
                const int q = qt + l15;
                const float val = accF[0] * S.rdiag[q];
                const float lab = 1.f - LABC * fabsf(tb - S.psS[q]);
                it_sum = fabsf(val - lab);
            }
            bfly_reduce2(tt_sum, it_sum);
            if (lane == 0) { S.redT[wave] = tt_sum; S.redI[wave] = it_sum; }
            __syncthreads();
            if (tid == 0) {
                partTT[b] = (double)(S.redT[0] + S.redT[1] + S.redT[2] + S.redT[3]);
                partIT[b] = (double)(S.redI[0] + S.redI[1] + S.redI[2] + S.redI[3]);
            }
        } else {
            if (tid == 0) { partTT[b] = 0.0; partIT[b] = 0.0; }
        }
    }

    // ---------------- completion-counter finalize (replaces k_final dispatch) ----------------
    __threadfence();                         // release: make this block's part visible
    if (tid == 0) {
        const unsigned done = atomicAdd(ctr, 1u);   // device-scope
        isLast = (done == GRID_TOTAL - 1) ? 1u : 0u;
    }
    __syncthreads();
    if (!isLast) return;
    __threadfence();                         // acquire: see all other blocks' parts

    double sII = 0.0, sTT = 0.0, sIT = 0.0;
    for (int i = tid; i < N_II; i += 256) sII += partII[i];
    for (int i = tid; i < N_TTSLOT; i += 256) { sTT += partTT[i]; sIT += partIT[i]; }
    float sM = maePart[tid] + maePart[tid + 256] + maePart[tid + 512] + maePart[tid + 768];

#pragma unroll
    for (int m = 1; m < 64; m <<= 1) {
        sII += __shfl_xor(sII, m, 64);
        sTT += __shfl_xor(sTT, m, 64);
        sIT += __shfl_xor(sIT, m, 64);
        sM  += __shfl_xor(sM, m, 64);
    }
    if (lane == 0) { finA[wave] = sII; finB[wave] = sTT; finC[wave] = sIT; finM[wave] = sM; }
    __syncthreads();
    if (tid == 0) {
        const double ii = finA[0] + finA[1] + finA[2] + finA[3];
        const double tt = finB[0] + finB[1] + finB[2] + finB[3];
        const double it = finC[0] + finC[1] + finC[2] + finC[3];
        out[0] = (float)(ii / (double)((size_t)B_N * B_N));        // image_image
        out[1] = (float)(tt / (double)((size_t)B_N * P_N * P_N));  // text_text
        out[2] = (float)(it / (double)((size_t)B_N * P_N));        // image_text
        out[3] = (finM[0] + finM[1] + finM[2] + finM[3]) * (1.f / B_N);  // mae
    }
}

extern "C" void kernel_launch(void* const* d_in, const int* in_sizes, int n_in,
                              void* d_out, int out_size, void* d_ws, size_t ws_size,
                              hipStream_t stream) {
    const float* pred  = (const float*)d_in[0];  // (B,)
    const float* targ  = (const float*)d_in[1];  // (B,)
    const float* feats = (const float*)d_in[2];  // (B,C)
    const float* pf    = (const float*)d_in[3];  // (B,P,C)
    const float* ps    = (const float*)d_in[4];  // (B,P)
    float* out = (float*)d_out;

    float* maePart      = (float*)d_ws;                               // 4 KB (1024 floats)
    double* partII      = (double*)((char*)d_ws + 4096);              // 528 doubles
    double* partTT      = (double*)((char*)d_ws + 16384);             // 4224 doubles
    double* partIT      = (double*)((char*)d_ws + 65536);             // 4224 doubles
    unsigned* ctr       = (unsigned*)((char*)d_ws + 102400);          // completion counter
    unsigned short* fb  = (unsigned short*)((char*)d_ws + 131072);    // f_norm bf16: 4 MB

    k_prep<<<B_N / 4, 256, 0, stream>>>(feats, pred, targ, fb, maePart, ctr);
    k_fused<<<GRID_TOTAL, 256, 0, stream>>>(pf, ps, targ, fb, partII, partTT, partIT,
                                            maePart, ctr, out);
}

// Round 4
// 468.964 us; speedup vs baseline: 2.4425x; 2.4425x over previous
//
#include <hip/hip_runtime.h>
#include <hip/hip_bf16.h>
#include <stdint.h>

// Sizes fixed by the problem
#define B_N 4096
#define P_N 32
#define C_N 512
#define LABC 0.1f       // 2/(ALPHA*NORM)
#define N_II 528        // 33*32/2 upper-triangle 128x128 tiles of the 4096x4096 Gram
// Interleave ii blocks 1-in-9 through the grid so the compute-bound ii tiles
// overlap the memory-bound pf stream.
#define GRID_TOTAL (N_II * 9)        // 4752
#define N_TTSLOT (GRID_TOTAL - N_II) // 4224 tt slots (4096 real + 128 zero-writers)

typedef float  floatx4 __attribute__((ext_vector_type(4)));
typedef __bf16 bf16x8  __attribute__((ext_vector_type(8)));

__device__ __forceinline__ unsigned short f2bf(float x) {
    return __builtin_bit_cast(unsigned short, __float2bfloat16(x));
}
__device__ __forceinline__ uint4 pack8(const float4& v0, const float4& v1) {
    uint4 pk;
    pk.x = (unsigned)f2bf(v0.x) | ((unsigned)f2bf(v0.y) << 16);
    pk.y = (unsigned)f2bf(v0.z) | ((unsigned)f2bf(v0.w) << 16);
    pk.z = (unsigned)f2bf(v1.x) | ((unsigned)f2bf(v1.y) << 16);
    pk.w = (unsigned)f2bf(v1.z) | ((unsigned)f2bf(v1.w) << 16);
    return pk;
}
__device__ __forceinline__ void bfly_reduce2(float& a, float& b) {
#pragma unroll
    for (int m = 1; m < 64; m <<= 1) {
        a += __shfl_xor(a, m, 64);
        b += __shfl_xor(b, m, 64);
    }
}
__device__ __forceinline__ void bfly_reduce1(float& a) {
#pragma unroll
    for (int m = 1; m < 64; m <<= 1) a += __shfl_xor(a, m, 64);
}

// ---------------- kernel A: normalize feats -> bf16, mae partials ----------------
__global__ __launch_bounds__(256) void k_prep(const float* __restrict__ feats,
                                              const float* __restrict__ pred,
                                              const float* __restrict__ targ,
                                              unsigned short* __restrict__ fb,
                                              float* __restrict__ maePart) {
    const int wave = threadIdx.x >> 6, lane = threadIdx.x & 63;
    const int row = blockIdx.x * 4 + wave;
    const float* src = feats + (size_t)row * C_N + lane * 8;
    float4 v0 = *(const float4*)src;
    float4 v1 = *(const float4*)(src + 4);
    float ss = v0.x*v0.x + v0.y*v0.y + v0.z*v0.z + v0.w*v0.w
             + v1.x*v1.x + v1.y*v1.y + v1.z*v1.z + v1.w*v1.w;
    bfly_reduce1(ss);
    const float inv = rsqrtf(fmaxf(ss, 1e-24f));
    float4 n0 = {v0.x*inv, v0.y*inv, v0.z*inv, v0.w*inv};
    float4 n1 = {v1.x*inv, v1.y*inv, v1.z*inv, v1.w*inv};
    *(uint4*)(fb + (size_t)row * C_N + lane * 8) = pack8(n0, n1);

    if (wave == 0) {  // mae partials for this block's 4 rows
        float v = 0.f;
        if (lane < 4) {
            const int r = blockIdx.x * 4 + lane;
            v = fabsf(pred[r] - targ[r]);
        }
        v += __shfl_xor(v, 1, 64);
        v += __shfl_xor(v, 2, 64);
        if (lane == 0) maePart[blockIdx.x] = v;
    }
}

// ---------------- kernel B: fused ii + tt/it, interleaved 1-in-9 ----------------
// tt path: NO LDS staging — MFMA operands are loaded directly from global in
// fragment layout (lane quad*16+l15 holds row pt+l15, floats [kk*32+quad*8,+8)).
// Unique bytes/block unchanged (64 KB); intra-block re-reads hit L1/L2.
#define APAD 130
struct TTsm {
    float psS[P_N];
    float rdiag[P_N];
    float redT[4], redI[4];
};
struct IIsm {
    unsigned short As[4 * APAD * 8];
    unsigned short Bs[4 * APAD * 8];
    float tm[128], tn[128];
    float red[4];
};
union SMu { TTsm tt; IIsm ii; };

__global__ __launch_bounds__(256) void k_fused(const float* __restrict__ pf_g,
                                               const float* __restrict__ ps_g,
                                               const float* __restrict__ targets,
                                               const unsigned short* __restrict__ fb,
                                               double* __restrict__ partII,
                                               double* __restrict__ partTT,
                                               double* __restrict__ partIT) {
    __shared__ __align__(16) SMu sm;
    const int tid = threadIdx.x, wave = tid >> 6, lane = tid & 63;
    const int quad = lane >> 4, l15 = lane & 15;
    const int bid = blockIdx.x;
    const bool isII = (bid % 9) == 0;

    if (isII) {
        // ================= image-image: 128x128 upper-triangle Gram tile =================
        IIsm& S = sm.ii;
        int bm = 0, rem = bid / 9;
        while (rem >= 32 - bm) { rem -= 32 - bm; ++bm; }
        const int bn = bm + rem;
        const int wr = wave >> 1, wc = wave & 1;
        const int mbase = bm * 128, nbase = bn * 128;

        if (tid < 128) S.tm[tid] = targets[mbase + tid];
        else           S.tn[tid - 128] = targets[nbase + tid - 128];

        const int row = tid >> 1, half = tid & 1;
        const unsigned short* aSrc = fb + (size_t)(mbase + row) * C_N + half * 16;
        const unsigned short* bSrc = fb + (size_t)(nbase + row) * C_N + half * 16;
        const int c0 = half * 2, c1 = half * 2 + 1;

        floatx4 accv[16];
#pragma unroll
        for (int i = 0; i < 16; ++i) accv[i] = (floatx4){0.f, 0.f, 0.f, 0.f};

        uint4 a0 = *(const uint4*)(aSrc);
        uint4 a1 = *(const uint4*)(aSrc + 8);
        uint4 b0 = *(const uint4*)(bSrc);
        uint4 b1 = *(const uint4*)(bSrc + 8);

        for (int ks = 0; ks < 16; ++ks) {
            __syncthreads();
            *(uint4*)&S.As[((size_t)c0 * APAD + row) * 8] = a0;
            *(uint4*)&S.As[((size_t)c1 * APAD + row) * 8] = a1;
            *(uint4*)&S.Bs[((size_t)c0 * APAD + row) * 8] = b0;
            *(uint4*)&S.Bs[((size_t)c1 * APAD + row) * 8] = b1;
            __syncthreads();
            if (ks < 15) {
                const int off = (ks + 1) * 32;
                a0 = *(const uint4*)(aSrc + off);
                a1 = *(const uint4*)(aSrc + off + 8);
                b0 = *(const uint4*)(bSrc + off);
                b1 = *(const uint4*)(bSrc + off + 8);
            }
            bf16x8 af[4], bfv[4];
#pragma unroll
            for (int t = 0; t < 4; ++t)
                af[t] = __builtin_bit_cast(bf16x8, *(const uint4*)&S.As[((size_t)quad * APAD + wr * 64 + t * 16 + l15) * 8]);
#pragma unroll
            for (int t = 0; t < 4; ++t)
                bfv[t] = __builtin_bit_cast(bf16x8, *(const uint4*)&S.Bs[((size_t)quad * APAD + wc * 64 + t * 16 + l15) * 8]);
#pragma unroll
            for (int ti = 0; ti < 4; ++ti)
#pragma unroll
                for (int tj = 0; tj < 4; ++tj)
                    accv[ti * 4 + tj] = __builtin_amdgcn_mfma_f32_16x16x32_bf16(af[ti], bfv[tj], accv[ti * 4 + tj], 0, 0, 0);
        }

        float s = 0.f;
#pragma unroll
        for (int ti = 0; ti < 4; ++ti)
#pragma unroll
            for (int tj = 0; tj < 4; ++tj)
#pragma unroll
                for (int r = 0; r < 4; ++r) {
                    const int p = wr * 64 + ti * 16 + quad * 4 + r;
                    const int q = wc * 64 + tj * 16 + l15;
                    const float lab = 1.f - LABC * fabsf(S.tm[p] - S.tn[q]);
                    s += fabsf(accv[ti * 4 + tj][r] - lab);
                }
        if (bm != bn) s *= 2.f;
        bfly_reduce1(s);
        if (lane == 0) S.red[wave] = s;
        __syncthreads();
        if (tid == 0) partII[bid / 9] = (double)(S.red[0] + S.red[1] + S.red[2] + S.red[3]);
    } else {
        // ================= text-text + image-text for one b (direct-load MFMA) =================
        const int b = bid - (bid / 9) - 1;   // dense 0..4223 over tt slots
        TTsm& S = sm.tt;
        if (b >= B_N) {
            if (tid == 0) { partTT[b] = 0.0; partIT[b] = 0.0; }
            return;
        }

        if (tid < P_N) S.psS[tid] = ps_g[b * P_N + tid];
        const float tb = targets[b];

        const int pt = (wave >> 1) * 16, qt = (wave & 1) * 16;
        const bool doF = (wave < 2);  // f-tile cols == qt for waves 0,1

        const float* rowA = pf_g + (size_t)b * P_N * C_N + (size_t)(pt + l15) * C_N;
        const float* rowB = pf_g + (size_t)b * P_N * C_N + (size_t)(qt + l15) * C_N;
        const unsigned short* fbrow = fb + (size_t)b * C_N;

        floatx4 acc4 = {0.f, 0.f, 0.f, 0.f};
        floatx4 accF = {0.f, 0.f, 0.f, 0.f};
        const uint4 zero4 = {0u, 0u, 0u, 0u};
#pragma unroll
        for (int kk = 0; kk < 16; ++kk) {
            const int off = kk * 32 + quad * 8;   // float index within the row
            const float4 a0 = *(const float4*)(rowA + off);
            const float4 a1 = *(const float4*)(rowA + off + 4);
            const float4 b0 = *(const float4*)(rowB + off);
            const float4 b1 = *(const float4*)(rowB + off + 4);
            const bf16x8 afrag = __builtin_bit_cast(bf16x8, pack8(a0, a1));
            const bf16x8 bfrag = __builtin_bit_cast(bf16x8, pack8(b0, b1));
            acc4 = __builtin_amdgcn_mfma_f32_16x16x32_bf16(afrag, bfrag, acc4, 0, 0, 0);
            if (doF) {
                // f-row chunk (bf16 already); same 16B for all lanes of a quad -> L1 broadcast
                const uint4 fr = *(const uint4*)(fbrow + off);
                const bf16x8 af = __builtin_bit_cast(bf16x8, (l15 == 0) ? fr : zero4);
                accF = __builtin_amdgcn_mfma_f32_16x16x32_bf16(af, bfrag, accF, 0, 0, 0);
            }
        }
        // diagonal -> rsqrt (tiles (0,0) wave0 and (16,16) wave3)
        if (pt == qt) {
            if ((l15 >> 2) == quad) S.rdiag[pt + l15] = rsqrtf(fmaxf(acc4[l15 & 3], 1e-24f));
        }
        __syncthreads();

        float tt_sum = 0.f, it_sum = 0.f;
#pragma unroll
        for (int r = 0; r < 4; ++r) {
            const int p = pt + quad * 4 + r;
            const int q = qt + l15;
            const float val = acc4[r] * S.rdiag[p] * S.rdiag[q];
            const float lab = 1.f - LABC * fabsf(S.psS[p] - S.psS[q]);
            tt_sum += fabsf(val - lab);
        }
        if (doF && quad == 0) {  // D row 0 of the f-tile: lanes quad==0, reg 0
            const int q = qt + l15;
            const float val = accF[0] * S.rdiag[q];
            const float lab = 1.f - LABC * fabsf(tb - S.psS[q]);
            it_sum = fabsf(val - lab);
        }
        bfly_reduce2(tt_sum, it_sum);
        if (lane == 0) { S.redT[wave] = tt_sum; S.redI[wave] = it_sum; }
        __syncthreads();
        if (tid == 0) {
            partTT[b] = (double)(S.redT[0] + S.redT[1] + S.redT[2] + S.redT[3]);
            partIT[b] = (double)(S.redI[0] + S.redI[1] + S.redI[2] + S.redI[3]);
        }
    }
}

// ---------------- kernel C: finalize (reduce partials, no atomics anywhere) ----------------
__global__ __launch_bounds__(256) void k_final(const double* __restrict__ partII,
                                               const double* __restrict__ partTT,
                                               const double* __restrict__ partIT,
                                               const float* __restrict__ maePart,
                                               float* __restrict__ out) {
    __shared__ double redA[4], redB[4], redC[4];
    __shared__ float redM[4];
    const int tid = threadIdx.x, wave = tid >> 6, lane = tid & 63;

    double sII = 0.0, sTT = 0.0, sIT = 0.0;
    for (int i = tid; i < N_II; i += 256) sII += partII[i];
    for (int i = tid; i < N_TTSLOT; i += 256) { sTT += partTT[i]; sIT += partIT[i]; }
    float sM = maePart[tid] + maePart[tid + 256] + maePart[tid + 512] + maePart[tid + 768];

#pragma unroll
    for (int m = 1; m < 64; m <<= 1) {
        sII += __shfl_xor(sII, m, 64);
        sTT += __shfl_xor(sTT, m, 64);
        sIT += __shfl_xor(sIT, m, 64);
        sM  += __shfl_xor(sM, m, 64);
    }
    if (lane == 0) { redA[wave] = sII; redB[wave] = sTT; redC[wave] = sIT; redM[wave] = sM; }
    __syncthreads();
    if (tid == 0) {
        const double ii = redA[0] + redA[1] + redA[2] + redA[3];
        const double tt = redB[0] + redB[1] + redB[2] + redB[3];
        const double it = redC[0] + redC[1] + redC[2] + redC[3];
        out[0] = (float)(ii / (double)((size_t)B_N * B_N));        // image_image
        out[1] = (float)(tt / (double)((size_t)B_N * P_N * P_N));  // text_text
        out[2] = (float)(it / (double)((size_t)B_N * P_N));        // image_text
        out[3] = (redM[0] + redM[1] + redM[2] + redM[3]) * (1.f / B_N);  // mae
    }
}

extern "C" void kernel_launch(void* const* d_in, const int* in_sizes, int n_in,
                              void* d_out, int out_size, void* d_ws, size_t ws_size,
                              hipStream_t stream) {
    const float* pred  = (const float*)d_in[0];  // (B,)
    const float* targ  = (const float*)d_in[1];  // (B,)
    const float* feats = (const float*)d_in[2];  // (B,C)
    const float* pf    = (const float*)d_in[3];  // (B,P,C)
    const float* ps    = (const float*)d_in[4];  // (B,P)
    float* out = (float*)d_out;

    float* maePart      = (float*)d_ws;                               // 4 KB (1024 floats)
    double* partII      = (double*)((char*)d_ws + 4096);              // 528 doubles
    double* partTT      = (double*)((char*)d_ws + 16384);             // 4224 doubles
    double* partIT      = (double*)((char*)d_ws + 65536);             // 4224 doubles
    unsigned short* fb  = (unsigned short*)((char*)d_ws + 131072);    // f_norm bf16: 4 MB

    k_prep<<<B_N / 4, 256, 0, stream>>>(feats, pred, targ, fb, maePart);
    k_fused<<<GRID_TOTAL, 256, 0, stream>>>(pf, ps, targ, fb, partII, partTT, partIT);
    k_final<<<1, 256, 0, stream>>>(partII, partTT, partIT, maePart, out);
}

// Round 5
// 387.179 us; speedup vs baseline: 2.9584x; 1.2112x over previous
//
#include <hip/hip_runtime.h>
#include <hip/hip_bf16.h>
#include <stdint.h>

// Sizes fixed by the problem
#define B_N 4096
#define P_N 32
#define C_N 512
#define LABC 0.1f       // 2/(ALPHA*NORM)
#define N_II 528        // 33*32/2 upper-triangle 128x128 tiles of the 4096x4096 Gram
// Interleave ii blocks 1-in-9 through the grid so the compute-bound ii tiles
// overlap the memory-bound pf stream.
#define GRID_TOTAL (N_II * 9)        // 4752
#define N_TTSLOT (GRID_TOTAL - N_II) // 4224 tt slots (4096 real + 128 zero-writers)

typedef float  floatx4 __attribute__((ext_vector_type(4)));
typedef __bf16 bf16x8  __attribute__((ext_vector_type(8)));

__device__ __forceinline__ unsigned short f2bf(float x) {
    return __builtin_bit_cast(unsigned short, __float2bfloat16(x));
}
__device__ __forceinline__ uint4 pack8(const float4& v0, const float4& v1) {
    uint4 pk;
    pk.x = (unsigned)f2bf(v0.x) | ((unsigned)f2bf(v0.y) << 16);
    pk.y = (unsigned)f2bf(v0.z) | ((unsigned)f2bf(v0.w) << 16);
    pk.z = (unsigned)f2bf(v1.x) | ((unsigned)f2bf(v1.y) << 16);
    pk.w = (unsigned)f2bf(v1.z) | ((unsigned)f2bf(v1.w) << 16);
    return pk;
}
__device__ __forceinline__ void bfly_reduce2(float& a, float& b) {
#pragma unroll
    for (int m = 1; m < 64; m <<= 1) {
        a += __shfl_xor(a, m, 64);
        b += __shfl_xor(b, m, 64);
    }
}
__device__ __forceinline__ void bfly_reduce1(float& a) {
#pragma unroll
    for (int m = 1; m < 64; m <<= 1) a += __shfl_xor(a, m, 64);
}

// ---------------- kernel A: normalize feats -> bf16, mae partials ----------------
__global__ __launch_bounds__(256) void k_prep(const float* __restrict__ feats,
                                              const float* __restrict__ pred,
                                              const float* __restrict__ targ,
                                              unsigned short* __restrict__ fb,
                                              float* __restrict__ maePart) {
    const int wave = threadIdx.x >> 6, lane = threadIdx.x & 63;
    const int row = blockIdx.x * 4 + wave;
    const float* src = feats + (size_t)row * C_N + lane * 8;
    float4 v0 = *(const float4*)src;
    float4 v1 = *(const float4*)(src + 4);
    float ss = v0.x*v0.x + v0.y*v0.y + v0.z*v0.z + v0.w*v0.w
             + v1.x*v1.x + v1.y*v1.y + v1.z*v1.z + v1.w*v1.w;
    bfly_reduce1(ss);
    const float inv = rsqrtf(fmaxf(ss, 1e-24f));
    float4 n0 = {v0.x*inv, v0.y*inv, v0.z*inv, v0.w*inv};
    float4 n1 = {v1.x*inv, v1.y*inv, v1.z*inv, v1.w*inv};
    *(uint4*)(fb + (size_t)row * C_N + lane * 8) = pack8(n0, n1);

    if (wave == 0) {  // mae partials for this block's 4 rows
        float v = 0.f;
        if (lane < 4) {
            const int r = blockIdx.x * 4 + lane;
            v = fabsf(pred[r] - targ[r]);
        }
        v += __shfl_xor(v, 1, 64);
        v += __shfl_xor(v, 2, 64);
        if (lane == 0) maePart[blockIdx.x] = v;
    }
}

// ---------------- kernel B: fused ii + tt/it, interleaved 1-in-9 ----------------
// tt path (K-split): each wave owns K-chunk [wave*128, +128) of all 32 pf rows,
// loads it as one 16-deep independent burst (same in-flight profile as r1),
// converts to bf16 in-register, and computes a PARTIAL 32x32 Gram with 24 MFMAs.
// Waves meet only at a f32 partial buffer: no LDS operand transpose, 2 barriers.
#define APAD 130
struct TTsm {
    float part[4][32][33];   // per-wave partial Gram (pad 33 vs bank conflicts)
    float partF[4][32];      // per-wave partial f-row (image-text)
    float psS[P_N];
    float rdiag[P_N];
    float redT[4], redI[4];
};
struct IIsm {
    unsigned short As[4 * APAD * 8];
    unsigned short Bs[4 * APAD * 8];
    float tm[128], tn[128];
    float red[4];
};
union SMu { TTsm tt; IIsm ii; };

__global__ __launch_bounds__(256, 4) void k_fused(const float* __restrict__ pf_g,
                                                  const float* __restrict__ ps_g,
                                                  const float* __restrict__ targets,
                                                  const unsigned short* __restrict__ fb,
                                                  double* __restrict__ partII,
                                                  double* __restrict__ partTT,
                                                  double* __restrict__ partIT) {
    __shared__ __align__(16) SMu sm;
    const int tid = threadIdx.x, wave = tid >> 6, lane = tid & 63;
    const int quad = lane >> 4, l15 = lane & 15;
    const int bid = blockIdx.x;
    const bool isII = (bid % 9) == 0;

    if (isII) {
        // ================= image-image: 128x128 upper-triangle Gram tile =================
        IIsm& S = sm.ii;
        int bm = 0, rem = bid / 9;
        while (rem >= 32 - bm) { rem -= 32 - bm; ++bm; }
        const int bn = bm + rem;
        const int wr = wave >> 1, wc = wave & 1;
        const int mbase = bm * 128, nbase = bn * 128;

        if (tid < 128) S.tm[tid] = targets[mbase + tid];
        else           S.tn[tid - 128] = targets[nbase + tid - 128];

        const int row = tid >> 1, half = tid & 1;
        const unsigned short* aSrc = fb + (size_t)(mbase + row) * C_N + half * 16;
        const unsigned short* bSrc = fb + (size_t)(nbase + row) * C_N + half * 16;
        const int c0 = half * 2, c1 = half * 2 + 1;

        floatx4 accv[16];
#pragma unroll
        for (int i = 0; i < 16; ++i) accv[i] = (floatx4){0.f, 0.f, 0.f, 0.f};

        uint4 a0 = *(const uint4*)(aSrc);
        uint4 a1 = *(const uint4*)(aSrc + 8);
        uint4 b0 = *(const uint4*)(bSrc);
        uint4 b1 = *(const uint4*)(bSrc + 8);

        for (int ks = 0; ks < 16; ++ks) {
            __syncthreads();
            *(uint4*)&S.As[((size_t)c0 * APAD + row) * 8] = a0;
            *(uint4*)&S.As[((size_t)c1 * APAD + row) * 8] = a1;
            *(uint4*)&S.Bs[((size_t)c0 * APAD + row) * 8] = b0;
            *(uint4*)&S.Bs[((size_t)c1 * APAD + row) * 8] = b1;
            __syncthreads();
            if (ks < 15) {
                const int off = (ks + 1) * 32;
                a0 = *(const uint4*)(aSrc + off);
                a1 = *(const uint4*)(aSrc + off + 8);
                b0 = *(const uint4*)(bSrc + off);
                b1 = *(const uint4*)(bSrc + off + 8);
            }
            bf16x8 af[4], bfv[4];
#pragma unroll
            for (int t = 0; t < 4; ++t)
                af[t] = __builtin_bit_cast(bf16x8, *(const uint4*)&S.As[((size_t)quad * APAD + wr * 64 + t * 16 + l15) * 8]);
#pragma unroll
            for (int t = 0; t < 4; ++t)
                bfv[t] = __builtin_bit_cast(bf16x8, *(const uint4*)&S.Bs[((size_t)quad * APAD + wc * 64 + t * 16 + l15) * 8]);
#pragma unroll
            for (int ti = 0; ti < 4; ++ti)
#pragma unroll
                for (int tj = 0; tj < 4; ++tj)
                    accv[ti * 4 + tj] = __builtin_amdgcn_mfma_f32_16x16x32_bf16(af[ti], bfv[tj], accv[ti * 4 + tj], 0, 0, 0);
        }

        float s = 0.f;
#pragma unroll
        for (int ti = 0; ti < 4; ++ti)
#pragma unroll
            for (int tj = 0; tj < 4; ++tj)
#pragma unroll
                for (int r = 0; r < 4; ++r) {
                    const int p = wr * 64 + ti * 16 + quad * 4 + r;
                    const int q = wc * 64 + tj * 16 + l15;
                    const float lab = 1.f - LABC * fabsf(S.tm[p] - S.tn[q]);
                    s += fabsf(accv[ti * 4 + tj][r] - lab);
                }
        if (bm != bn) s *= 2.f;
        bfly_reduce1(s);
        if (lane == 0) S.red[wave] = s;
        __syncthreads();
        if (tid == 0) partII[bid / 9] = (double)(S.red[0] + S.red[1] + S.red[2] + S.red[3]);
    } else {
        // ================= text-text + image-text for one b (K-split waves) =================
        const int b = bid - (bid / 9) - 1;   // dense 0..4223 over tt slots
        TTsm& S = sm.tt;
        if (b >= B_N) {
            if (tid == 0) { partTT[b] = 0.0; partIT[b] = 0.0; }
            return;
        }

        if (tid < P_N) S.psS[tid] = ps_g[b * P_N + tid];
        const float tb = targets[b];

        // Burst-load this wave's K-chunk of all 32 rows: 16 independent 16B loads.
        const float* rowLo = pf_g + (size_t)b * P_N * C_N + (size_t)l15 * C_N + wave * 128 + quad * 8;
        const float* rowHi = rowLo + 16 * C_N;
        float4 lo[4][2], hi[4][2];
#pragma unroll
        for (int kk = 0; kk < 4; ++kk) {
            lo[kk][0] = *(const float4*)(rowLo + kk * 32);
            lo[kk][1] = *(const float4*)(rowLo + kk * 32 + 4);
        }
#pragma unroll
        for (int kk = 0; kk < 4; ++kk) {
            hi[kk][0] = *(const float4*)(rowHi + kk * 32);
            hi[kk][1] = *(const float4*)(rowHi + kk * 32 + 4);
        }
        // f_norm chunks (bf16): only A-row-0 lanes (l15==0) carry data.
        const uint4 zero4 = {0u, 0u, 0u, 0u};
        uint4 fq[4] = {zero4, zero4, zero4, zero4};
        if (l15 == 0) {
            const unsigned short* fp = fb + (size_t)b * C_N + wave * 128 + quad * 8;
#pragma unroll
            for (int kk = 0; kk < 4; ++kk) fq[kk] = *(const uint4*)(fp + kk * 32);
        }

        floatx4 a00 = {0.f,0.f,0.f,0.f}, a01 = a00, a10 = a00, a11 = a00, f0 = a00, f1 = a00;
#pragma unroll
        for (int kk = 0; kk < 4; ++kk) {
            const bf16x8 aL = __builtin_bit_cast(bf16x8, pack8(lo[kk][0], lo[kk][1]));
            const bf16x8 aH = __builtin_bit_cast(bf16x8, pack8(hi[kk][0], hi[kk][1]));
            a00 = __builtin_amdgcn_mfma_f32_16x16x32_bf16(aL, aL, a00, 0, 0, 0);
            a01 = __builtin_amdgcn_mfma_f32_16x16x32_bf16(aL, aH, a01, 0, 0, 0);
            a10 = __builtin_amdgcn_mfma_f32_16x16x32_bf16(aH, aL, a10, 0, 0, 0);
            a11 = __builtin_amdgcn_mfma_f32_16x16x32_bf16(aH, aH, a11, 0, 0, 0);
            const bf16x8 af = __builtin_bit_cast(bf16x8, fq[kk]);
            f0 = __builtin_amdgcn_mfma_f32_16x16x32_bf16(af, aL, f0, 0, 0, 0);
            f1 = __builtin_amdgcn_mfma_f32_16x16x32_bf16(af, aH, f1, 0, 0, 0);
        }

        // Write partial Gram: D cell (row quad*4+r, col l15) per 16x16 tile.
        float (*P)[33] = S.part[wave];
#pragma unroll
        for (int r = 0; r < 4; ++r) {
            const int pr = quad * 4 + r;
            P[pr][l15]           = a00[r];
            P[pr][16 + l15]      = a01[r];
            P[16 + pr][l15]      = a10[r];
            P[16 + pr][16 + l15] = a11[r];
        }
        if (quad == 0) { S.partF[wave][l15] = f0[0]; S.partF[wave][16 + l15] = f1[0]; }
        __syncthreads();

        // Reduce 4 wave-partials; each thread owns 4 of the 1024 cells.
        float cell[4]; int cp[4], cq[4];
#pragma unroll
        for (int i = 0; i < 4; ++i) {
            const int c = tid + i * 256;
            const int p = c >> 5, qc = c & 31;
            const float v = S.part[0][p][qc] + S.part[1][p][qc]
                          + S.part[2][p][qc] + S.part[3][p][qc];
            cell[i] = v; cp[i] = p; cq[i] = qc;
            if (p == qc) S.rdiag[p] = rsqrtf(fmaxf(v, 1e-24f));
        }
        __syncthreads();

        float tt_sum = 0.f, it_sum = 0.f;
#pragma unroll
        for (int i = 0; i < 4; ++i) {
            const float val = cell[i] * S.rdiag[cp[i]] * S.rdiag[cq[i]];
            const float lab = 1.f - LABC * fabsf(S.psS[cp[i]] - S.psS[cq[i]]);
            tt_sum += fabsf(val - lab);
        }
        if (tid < P_N) {
            const float fs = S.partF[0][tid] + S.partF[1][tid]
                           + S.partF[2][tid] + S.partF[3][tid];
            const float val = fs * S.rdiag[tid];
            const float lab = 1.f - LABC * fabsf(tb - S.psS[tid]);
            it_sum = fabsf(val - lab);
        }
        bfly_reduce2(tt_sum, it_sum);
        if (lane == 0) { S.redT[wave] = tt_sum; S.redI[wave] = it_sum; }
        __syncthreads();
        if (tid == 0) {
            partTT[b] = (double)(S.redT[0] + S.redT[1] + S.redT[2] + S.redT[3]);
            partIT[b] = (double)(S.redI[0] + S.redI[1] + S.redI[2] + S.redI[3]);
        }
    }
}

// ---------------- kernel C: finalize (reduce partials, no atomics anywhere) ----------------
__global__ __launch_bounds__(256) void k_final(const double* __restrict__ partII,
                                               const double* __restrict__ partTT,
                                               const double* __restrict__ partIT,
                                               const float* __restrict__ maePart,
                                               float* __restrict__ out) {
    __shared__ double redA[4], redB[4], redC[4];
    __shared__ float redM[4];
    const int tid = threadIdx.x, wave = tid >> 6, lane = tid & 63;

    double sII = 0.0, sTT = 0.0, sIT = 0.0;
    for (int i = tid; i < N_II; i += 256) sII += partII[i];
    for (int i = tid; i < N_TTSLOT; i += 256) { sTT += partTT[i]; sIT += partIT[i]; }
    float sM = maePart[tid] + maePart[tid + 256] + maePart[tid + 512] + maePart[tid + 768];

#pragma unroll
    for (int m = 1; m < 64; m <<= 1) {
        sII += __shfl_xor(sII, m, 64);
        sTT += __shfl_xor(sTT, m, 64);
        sIT += __shfl_xor(sIT, m, 64);
        sM  += __shfl_xor(sM, m, 64);
    }
    if (lane == 0) { redA[wave] = sII; redB[wave] = sTT; redC[wave] = sIT; redM[wave] = sM; }
    __syncthreads();
    if (tid == 0) {
        const double ii = redA[0] + redA[1] + redA[2] + redA[3];
        const double tt = redB[0] + redB[1] + redB[2] + redB[3];
        const double it = redC[0] + redC[1] + redC[2] + redC[3];
        out[0] = (float)(ii / (double)((size_t)B_N * B_N));        // image_image
        out[1] = (float)(tt / (double)((size_t)B_N * P_N * P_N));  // text_text
        out[2] = (float)(it / (double)((size_t)B_N * P_N));        // image_text
        out[3] = (redM[0] + redM[1] + redM[2] + redM[3]) * (1.f / B_N);  // mae
    }
}

extern "C" void kernel_launch(void* const* d_in, const int* in_sizes, int n_in,
                              void* d_out, int out_size, void* d_ws, size_t ws_size,
                              hipStream_t stream) {
    const float* pred  = (const float*)d_in[0];  // (B,)
    const float* targ  = (const float*)d_in[1];  // (B,)
    const float* feats = (const float*)d_in[2];  // (B,C)
    const float* pf    = (const float*)d_in[3];  // (B,P,C)
    const float* ps    = (const float*)d_in[4];  // (B,P)
    float* out = (float*)d_out;

    float* maePart      = (float*)d_ws;                               // 4 KB (1024 floats)
    double* partII      = (double*)((char*)d_ws + 4096);              // 528 doubles
    double* partTT      = (double*)((char*)d_ws + 16384);             // 4224 doubles
    double* partIT      = (double*)((char*)d_ws + 65536);             // 4224 doubles
    unsigned short* fb  = (unsigned short*)((char*)d_ws + 131072);    // f_norm bf16: 4 MB

    k_prep<<<B_N / 4, 256, 0, stream>>>(feats, pred, targ, fb, maePart);
    k_fused<<<GRID_TOTAL, 256, 0, stream>>>(pf, ps, targ, fb, partII, partTT, partIT);
    k_final<<<1, 256, 0, stream>>>(partII, partTT, partIT, maePart, out);
}